// Round 13
// baseline (43.561 us; speedup 1.0000x reference)
//
#include <hip/hip_runtime.h>
#include <math.h>

#define BB 512
#define SS 200
#define DD 64
#define VV 100000
#define NT 384   // 6 waves: 0-3 compute, 4-5 store

__device__ __forceinline__ float gauss_pdf(float xx, float mu, float sg) {
    float z = (xx - mu) / sg;
    return expf(-0.5f * z * z - logf(sg) - 0.9189385332046727f);
}

// tanh(x) = 1 - 2/(exp(2x)+1). Branch-free: exp->inf gives 1, exp->0 gives -1.
__device__ __forceinline__ float fast_tanh(float x) {
    float e = __expf(2.f * x);
    return 1.f - 2.f / (e + 1.f);
}

// v13 = v12 + doubled store-wave parallelism (waves 4-5, 4 store waves/CU)
// to saturate the per-CU HBM write share; Wq staging confined to the compute
// waves so store waves enter their role immediately after the barriers.
__global__ __launch_bounds__(NT, 2) void fused_v13(
    const float* __restrict__ x, const int* __restrict__ x_ids,
    const float* __restrict__ tg, const int* __restrict__ cla,
    const float* __restrict__ Wq, const float* __restrict__ bq,
    const float* __restrict__ Wk, const float* __restrict__ bk,
    const float* __restrict__ wv, const float* __restrict__ bv,
    const float* __restrict__ theta, float* __restrict__ out)
{
    const int b    = blockIdx.x;
    const int tid  = threadIdx.x;
    const int lane = tid & 63;
    const int wave = tid >> 6;

    __shared__ float sWq[DD * DD];   // 16 KB, row-major [j][d]
    __shared__ float sx0[DD];
    __shared__ float sKp[4][DD];
    __shared__ float sK[DD];
    __shared__ float sWv[DD];
    __shared__ float sScore[SS];
    __shared__ float sRed[8];
    __shared__ float sTh[17];

    const float* __restrict__ xb = x + (size_t)b * SS * DD;
    float* __restrict__ orow = out + (size_t)b * VV;

    // ---- compute threads' x-row into 16 NAMED float4 regs (64 VGPRs) ----
    float4 xr0 = {0,0,0,0}, xr1 = {0,0,0,0}, xr2 = {0,0,0,0}, xr3 = {0,0,0,0},
           xr4 = {0,0,0,0}, xr5 = {0,0,0,0}, xr6 = {0,0,0,0}, xr7 = {0,0,0,0},
           xr8 = {0,0,0,0}, xr9 = {0,0,0,0}, xr10= {0,0,0,0}, xr11= {0,0,0,0},
           xr12= {0,0,0,0}, xr13= {0,0,0,0}, xr14= {0,0,0,0}, xr15= {0,0,0,0};
    if (tid < SS) {
        const float4* __restrict__ xp = (const float4*)(xb + tid * DD);
        xr0 = xp[0];  xr1 = xp[1];  xr2 = xp[2];  xr3 = xp[3];
        xr4 = xp[4];  xr5 = xp[5];  xr6 = xp[6];  xr7 = xp[7];
        xr8 = xp[8];  xr9 = xp[9];  xr10= xp[10]; xr11= xp[11];
        xr12= xp[12]; xr13= xp[13]; xr14= xp[14]; xr15= xp[15];
    }

    // ---- stage Wq (compute waves only) / x0 / wv / theta ----
    if (wave < 4) {
        const float4* __restrict__ Wq4 = (const float4*)Wq;
        float4* __restrict__ sWq4 = (float4*)sWq;
        #pragma unroll
        for (int c = 0; c < 4; ++c) sWq4[tid + 256 * c] = Wq4[tid + 256 * c];
    }
    if (tid < DD) sx0[tid] = xb[tid];
    if (tid >= 64 && tid < 128) sWv[tid - 64] = wv[tid - 64];
    if (tid >= 128 && tid < 145) sTh[tid - 128] = theta[tid - 128];
    __syncthreads();

    // ---- k partials: waves 0-3, wave w covers j in [16w,16w+16); lane = d --
    if (wave < 4) {
        float acc = 0.f;
        #pragma unroll
        for (int jj = 0; jj < 16; ++jj) {
            int j = wave * 16 + jj;
            acc = fmaf(sx0[j], Wk[j * DD + lane], acc);
        }
        sKp[wave][lane] = acc;
    }
    __syncthreads();
    if (tid < DD)
        sK[tid] = sKp[0][tid] + sKp[1][tid] + sKp[2][tid] + sKp[3][tid]
                + bq[tid] + bk[tid];
    __syncthreads();
    // ======== roles diverge; re-merge at the pre-softmax barrier ========

    if (tid >= 256) {
        // ---- store role (waves 4-5): zero this block's 400 KB row ----
        float4* __restrict__ orow4 = (float4*)orow;
        const float4 z4 = make_float4(0.f, 0.f, 0.f, 0.f);
        for (int i = tid - 256; i < VV / 4; i += 128)
            orow4[i] = z4;
    } else if (tid < SS) {
        // ---- compute role: fused GEMV + tanh + wv-dot, thread t = row t ----
        const float4* __restrict__ W4 = (const float4*)sWq; // [j][16 x float4]
        const float bvv = bv[0];
        float scacc = 0.f;
        for (int g = 0; g < 16; ++g) {        // d-group: d = 4g..4g+3
            float a0 = 0.f, a1 = 0.f, a2 = 0.f, a3 = 0.f;
#define STEP(J, XJ) { float4 w = W4[(J)*16 + g]; \
    a0 = fmaf(XJ, w.x, a0); a1 = fmaf(XJ, w.y, a1); \
    a2 = fmaf(XJ, w.z, a2); a3 = fmaf(XJ, w.w, a3); }
            STEP(0, xr0.x)  STEP(1, xr0.y)  STEP(2, xr0.z)  STEP(3, xr0.w)
            STEP(4, xr1.x)  STEP(5, xr1.y)  STEP(6, xr1.z)  STEP(7, xr1.w)
            STEP(8, xr2.x)  STEP(9, xr2.y)  STEP(10,xr2.z)  STEP(11,xr2.w)
            STEP(12,xr3.x)  STEP(13,xr3.y)  STEP(14,xr3.z)  STEP(15,xr3.w)
            STEP(16,xr4.x)  STEP(17,xr4.y)  STEP(18,xr4.z)  STEP(19,xr4.w)
            STEP(20,xr5.x)  STEP(21,xr5.y)  STEP(22,xr5.z)  STEP(23,xr5.w)
            STEP(24,xr6.x)  STEP(25,xr6.y)  STEP(26,xr6.z)  STEP(27,xr6.w)
            STEP(28,xr7.x)  STEP(29,xr7.y)  STEP(30,xr7.z)  STEP(31,xr7.w)
            STEP(32,xr8.x)  STEP(33,xr8.y)  STEP(34,xr8.z)  STEP(35,xr8.w)
            STEP(36,xr9.x)  STEP(37,xr9.y)  STEP(38,xr9.z)  STEP(39,xr9.w)
            STEP(40,xr10.x) STEP(41,xr10.y) STEP(42,xr10.z) STEP(43,xr10.w)
            STEP(44,xr11.x) STEP(45,xr11.y) STEP(46,xr11.z) STEP(47,xr11.w)
            STEP(48,xr12.x) STEP(49,xr12.y) STEP(50,xr12.z) STEP(51,xr12.w)
            STEP(52,xr13.x) STEP(53,xr13.y) STEP(54,xr13.z) STEP(55,xr13.w)
            STEP(56,xr14.x) STEP(57,xr14.y) STEP(58,xr14.z) STEP(59,xr14.w)
            STEP(60,xr15.x) STEP(61,xr15.y) STEP(62,xr15.z) STEP(63,xr15.w)
#undef STEP
            const int d = 4 * g;
            scacc = fmaf(fast_tanh(a0 + sK[d+0]), sWv[d+0], scacc);
            scacc = fmaf(fast_tanh(a1 + sK[d+1]), sWv[d+1], scacc);
            scacc = fmaf(fast_tanh(a2 + sK[d+2]), sWv[d+2], scacc);
            scacc = fmaf(fast_tanh(a3 + sK[d+3]), sWv[d+3], scacc);
        }
        int id = x_ids[b * SS + tid];
        sScore[tid] = (id == 0 || id == 1) ? -INFINITY : (scacc + bvv);
    }
    __syncthreads();   // scores ready AND store waves' zeros drained

    // ---- block softmax over 200 scores (tid == s) ----
    float sc = (tid < SS) ? sScore[tid] : -INFINITY;
    float m = sc;
    #pragma unroll
    for (int off = 32; off > 0; off >>= 1) m = fmaxf(m, __shfl_xor(m, off));
    if (lane == 0 && wave < 4) sRed[wave] = m;
    __syncthreads();
    const float M = fmaxf(fmaxf(sRed[0], sRed[1]), fmaxf(sRed[2], sRed[3]));
    float e = (tid < SS) ? expf(sc - M) : 0.f;
    float ssum = e;
    #pragma unroll
    for (int off = 32; off > 0; off >>= 1) ssum += __shfl_xor(ssum, off);
    if (lane == 0 && wave < 4) sRed[4 + wave] = ssum;
    __syncthreads();
    const float Z = sRed[4] + sRed[5] + sRed[6] + sRed[7];

    const float wpg = sTh[6];

    // p_repeat scatter into this block's own (already-zeroed) row
    if (tid < SS && e > 0.f) {
        int id = x_ids[b * SS + tid];
        atomicAdd(orow + id, (1.f - wpg) * (e / Z));
    }

    // p_gap scatter at ids x_ids[:, 1:]
    if (tid < SS - 1) {
        float t  = tg[b * (SS - 1) + tid];
        int   c  = cla[b * (SS - 1) + tid];
        float c0 = (c == 0) ? t : 180.f;
        float c1 = (c == 1) ? t : 180.f;
        float c2 = (c == 2) ? t : 180.f;
        float g = sTh[0] * gauss_pdf(c0, sTh[7],  sTh[8])
                + sTh[1] * gauss_pdf(c1, sTh[9],  sTh[10])
                + sTh[2] * gauss_pdf(c1, sTh[11], sTh[12])
                + sTh[3] * gauss_pdf(c2, sTh[13], sTh[14])
                + sTh[4] * powf(c2, sTh[15]);
        int id = x_ids[b * SS + tid + 1];
        atomicAdd(orow + id, wpg * g);
    }
}

extern "C" void kernel_launch(void* const* d_in, const int* in_sizes, int n_in,
                              void* d_out, int out_size, void* d_ws, size_t ws_size,
                              hipStream_t stream) {
    const float* x     = (const float*)d_in[0];
    const int*   x_ids = (const int*)d_in[1];
    const float* tgp   = (const float*)d_in[2];
    const int*   cl    = (const int*)d_in[3];
    const float* Wq    = (const float*)d_in[4];
    const float* bq    = (const float*)d_in[5];
    const float* Wk    = (const float*)d_in[6];
    const float* bk    = (const float*)d_in[7];
    const float* wv    = (const float*)d_in[8];
    const float* bv    = (const float*)d_in[9];
    const float* th    = (const float*)d_in[10];
    float* out = (float*)d_out;

    hipLaunchKernelGGL(fused_v13, dim3(BB), dim3(NT), 0, stream,
                       x, x_ids, tgp, cl, Wq, bq, Wk, bk, wv, bv, th, out);
}

// Round 14
// 43.351 us; speedup vs baseline: 1.0048x; 1.0048x over previous
//
#include <hip/hip_runtime.h>
#include <math.h>

#define BB 512
#define SS 200
#define DD 64
#define VV 100000
#define NT 384   // 6 waves: 0-3 compute, 4-5 store

// pre-store batch sizes (iterations of the 128-thread store stride)
#define PRE_A 16
#define PRE_B 8
#define PRE_C 8
#define PRE_TOT (PRE_A + PRE_B + PRE_C)

__device__ __forceinline__ float gauss_pdf(float xx, float mu, float sg) {
    float z = (xx - mu) / sg;
    return expf(-0.5f * z * z - logf(sg) - 0.9189385332046727f);
}

// tanh(x) = 1 - 2/(exp(2x)+1). Branch-free: exp->inf gives 1, exp->0 gives -1.
__device__ __forceinline__ float fast_tanh(float x) {
    float e = __expf(2.f * x);
    return 1.f - 2.f / (e + 1.f);
}

// v14 = v13 + (1) pre-store batches drained at the head barriers (moves ~64KB
// per block of the write drain under the staging/k-partial phase) and
// (2) gap-gauss precompute hidden in the compute waves' idle window before
// the pre-softmax barrier (powf chain off the serial tail).
__global__ __launch_bounds__(NT, 2) void fused_v14(
    const float* __restrict__ x, const int* __restrict__ x_ids,
    const float* __restrict__ tg, const int* __restrict__ cla,
    const float* __restrict__ Wq, const float* __restrict__ bq,
    const float* __restrict__ Wk, const float* __restrict__ bk,
    const float* __restrict__ wv, const float* __restrict__ bv,
    const float* __restrict__ theta, float* __restrict__ out)
{
    const int b    = blockIdx.x;
    const int tid  = threadIdx.x;
    const int lane = tid & 63;
    const int wave = tid >> 6;

    __shared__ float sWq[DD * DD];   // 16 KB, row-major [j][d]
    __shared__ float sx0[DD];
    __shared__ float sKp[4][DD];
    __shared__ float sK[DD];
    __shared__ float sWv[DD];
    __shared__ float sScore[SS];
    __shared__ float sGap[SS];       // precomputed wpg * g per gap slot
    __shared__ float sRed[8];
    __shared__ float sTh[17];

    const float* __restrict__ xb = x + (size_t)b * SS * DD;
    float* __restrict__ orow = out + (size_t)b * VV;
    float4* __restrict__ orow4 = (float4*)orow;
    const float4 z4 = make_float4(0.f, 0.f, 0.f, 0.f);

    // ---- compute threads' x-row into 16 NAMED float4 regs (64 VGPRs) ----
    float4 xr0 = {0,0,0,0}, xr1 = {0,0,0,0}, xr2 = {0,0,0,0}, xr3 = {0,0,0,0},
           xr4 = {0,0,0,0}, xr5 = {0,0,0,0}, xr6 = {0,0,0,0}, xr7 = {0,0,0,0},
           xr8 = {0,0,0,0}, xr9 = {0,0,0,0}, xr10= {0,0,0,0}, xr11= {0,0,0,0},
           xr12= {0,0,0,0}, xr13= {0,0,0,0}, xr14= {0,0,0,0}, xr15= {0,0,0,0};
    if (tid < SS) {
        const float4* __restrict__ xp = (const float4*)(xb + tid * DD);
        xr0 = xp[0];  xr1 = xp[1];  xr2 = xp[2];  xr3 = xp[3];
        xr4 = xp[4];  xr5 = xp[5];  xr6 = xp[6];  xr7 = xp[7];
        xr8 = xp[8];  xr9 = xp[9];  xr10= xp[10]; xr11= xp[11];
        xr12= xp[12]; xr13= xp[13]; xr14= xp[14]; xr15= xp[15];
    }

    // ---- stage Wq (compute waves) / x0 / wv / theta; pre-store batch A ----
    if (wave < 4) {
        const float4* __restrict__ Wq4 = (const float4*)Wq;
        float4* __restrict__ sWq4 = (float4*)sWq;
        #pragma unroll
        for (int c = 0; c < 4; ++c) sWq4[tid + 256 * c] = Wq4[tid + 256 * c];
    } else {
        const int st = tid - 256;           // 0..127
        #pragma unroll
        for (int it = 0; it < PRE_A; ++it)
            orow4[st + 128 * it] = z4;
    }
    if (tid < DD) sx0[tid] = xb[tid];
    if (tid >= 64 && tid < 128) sWv[tid - 64] = wv[tid - 64];
    if (tid >= 128 && tid < 145) sTh[tid - 128] = theta[tid - 128];
    __syncthreads();   // B1: batch A drains under the staging above

    // ---- k partials (waves 0-3); store waves: batch B ----
    if (wave < 4) {
        float acc = 0.f;
        #pragma unroll
        for (int jj = 0; jj < 16; ++jj) {
            int j = wave * 16 + jj;
            acc = fmaf(sx0[j], Wk[j * DD + lane], acc);
        }
        sKp[wave][lane] = acc;
    } else {
        const int st = tid - 256;
        #pragma unroll
        for (int it = PRE_A; it < PRE_A + PRE_B; ++it)
            orow4[st + 128 * it] = z4;
    }
    __syncthreads();   // B2
    if (tid < DD)
        sK[tid] = sKp[0][tid] + sKp[1][tid] + sKp[2][tid] + sKp[3][tid]
                + bq[tid] + bk[tid];
    else if (wave >= 4) {
        const int st = tid - 256;
        #pragma unroll
        for (int it = PRE_A + PRE_B; it < PRE_TOT; ++it)
            orow4[st + 128 * it] = z4;
    }
    __syncthreads();   // B3
    // ======== roles diverge; re-merge at the pre-softmax barrier ========

    if (tid >= 256) {
        // ---- store role: remaining zeros (from stride PRE_TOT) ----
        for (int i = (tid - 256) + 128 * PRE_TOT; i < VV / 4; i += 128)
            orow4[i] = z4;
    } else if (tid < SS) {
        // ---- compute role: fused GEMV + tanh + wv-dot, thread t = row t ----
        const float4* __restrict__ W4 = (const float4*)sWq; // [j][16 x float4]
        const float bvv = bv[0];
        float scacc = 0.f;
        for (int g = 0; g < 16; ++g) {        // d-group: d = 4g..4g+3
            float a0 = 0.f, a1 = 0.f, a2 = 0.f, a3 = 0.f;
#define STEP(J, XJ) { float4 w = W4[(J)*16 + g]; \
    a0 = fmaf(XJ, w.x, a0); a1 = fmaf(XJ, w.y, a1); \
    a2 = fmaf(XJ, w.z, a2); a3 = fmaf(XJ, w.w, a3); }
            STEP(0, xr0.x)  STEP(1, xr0.y)  STEP(2, xr0.z)  STEP(3, xr0.w)
            STEP(4, xr1.x)  STEP(5, xr1.y)  STEP(6, xr1.z)  STEP(7, xr1.w)
            STEP(8, xr2.x)  STEP(9, xr2.y)  STEP(10,xr2.z)  STEP(11,xr2.w)
            STEP(12,xr3.x)  STEP(13,xr3.y)  STEP(14,xr3.z)  STEP(15,xr3.w)
            STEP(16,xr4.x)  STEP(17,xr4.y)  STEP(18,xr4.z)  STEP(19,xr4.w)
            STEP(20,xr5.x)  STEP(21,xr5.y)  STEP(22,xr5.z)  STEP(23,xr5.w)
            STEP(24,xr6.x)  STEP(25,xr6.y)  STEP(26,xr6.z)  STEP(27,xr6.w)
            STEP(28,xr7.x)  STEP(29,xr7.y)  STEP(30,xr7.z)  STEP(31,xr7.w)
            STEP(32,xr8.x)  STEP(33,xr8.y)  STEP(34,xr8.z)  STEP(35,xr8.w)
            STEP(36,xr9.x)  STEP(37,xr9.y)  STEP(38,xr9.z)  STEP(39,xr9.w)
            STEP(40,xr10.x) STEP(41,xr10.y) STEP(42,xr10.z) STEP(43,xr10.w)
            STEP(44,xr11.x) STEP(45,xr11.y) STEP(46,xr11.z) STEP(47,xr11.w)
            STEP(48,xr12.x) STEP(49,xr12.y) STEP(50,xr12.z) STEP(51,xr12.w)
            STEP(52,xr13.x) STEP(53,xr13.y) STEP(54,xr13.z) STEP(55,xr13.w)
            STEP(56,xr14.x) STEP(57,xr14.y) STEP(58,xr14.z) STEP(59,xr14.w)
            STEP(60,xr15.x) STEP(61,xr15.y) STEP(62,xr15.z) STEP(63,xr15.w)
#undef STEP
            const int d = 4 * g;
            scacc = fmaf(fast_tanh(a0 + sK[d+0]), sWv[d+0], scacc);
            scacc = fmaf(fast_tanh(a1 + sK[d+1]), sWv[d+1], scacc);
            scacc = fmaf(fast_tanh(a2 + sK[d+2]), sWv[d+2], scacc);
            scacc = fmaf(fast_tanh(a3 + sK[d+3]), sWv[d+3], scacc);
        }
        int id = x_ids[b * SS + tid];
        sScore[tid] = (id == 0 || id == 1) ? -INFINITY : (scacc + bvv);
    }

    // ---- gap-gauss precompute: hidden in the compute waves' idle window ----
    if (tid < SS - 1) {
        float t  = tg[b * (SS - 1) + tid];
        int   c  = cla[b * (SS - 1) + tid];
        float c0 = (c == 0) ? t : 180.f;
        float c1 = (c == 1) ? t : 180.f;
        float c2 = (c == 2) ? t : 180.f;
        float g = sTh[0] * gauss_pdf(c0, sTh[7],  sTh[8])
                + sTh[1] * gauss_pdf(c1, sTh[9],  sTh[10])
                + sTh[2] * gauss_pdf(c1, sTh[11], sTh[12])
                + sTh[3] * gauss_pdf(c2, sTh[13], sTh[14])
                + sTh[4] * powf(c2, sTh[15]);
        sGap[tid] = sTh[6] * g;
    }
    __syncthreads();   // B4: scores+gaps ready AND all zeros drained

    // ---- block softmax over 200 scores (tid == s) ----
    float sc = (tid < SS) ? sScore[tid] : -INFINITY;
    float m = sc;
    #pragma unroll
    for (int off = 32; off > 0; off >>= 1) m = fmaxf(m, __shfl_xor(m, off));
    if (lane == 0 && wave < 4) sRed[wave] = m;
    __syncthreads();
    const float M = fmaxf(fmaxf(sRed[0], sRed[1]), fmaxf(sRed[2], sRed[3]));
    float e = (tid < SS) ? expf(sc - M) : 0.f;
    float ssum = e;
    #pragma unroll
    for (int off = 32; off > 0; off >>= 1) ssum += __shfl_xor(ssum, off);
    if (lane == 0 && wave < 4) sRed[4 + wave] = ssum;
    __syncthreads();
    const float Z = sRed[4] + sRed[5] + sRed[6] + sRed[7];

    const float wpg = sTh[6];

    // p_repeat scatter into this block's own (already-zeroed) row
    if (tid < SS && e > 0.f) {
        int id = x_ids[b * SS + tid];
        atomicAdd(orow + id, (1.f - wpg) * (e / Z));
    }

    // p_gap scatter: value precomputed, tail is just the atomic
    if (tid < SS - 1) {
        int id = x_ids[b * SS + tid + 1];
        atomicAdd(orow + id, sGap[tid]);
    }
}

extern "C" void kernel_launch(void* const* d_in, const int* in_sizes, int n_in,
                              void* d_out, int out_size, void* d_ws, size_t ws_size,
                              hipStream_t stream) {
    const float* x     = (const float*)d_in[0];
    const int*   x_ids = (const int*)d_in[1];
    const float* tgp   = (const float*)d_in[2];
    const int*   cl    = (const int*)d_in[3];
    const float* Wq    = (const float*)d_in[4];
    const float* bq    = (const float*)d_in[5];
    const float* Wk    = (const float*)d_in[6];
    const float* bk    = (const float*)d_in[7];
    const float* wv    = (const float*)d_in[8];
    const float* bv    = (const float*)d_in[9];
    const float* th    = (const float*)d_in[10];
    float* out = (float*)d_out;

    hipLaunchKernelGGL(fused_v14, dim3(BB), dim3(NT), 0, stream,
                       x, x_ids, tgp, cl, Wq, bq, Wk, bk, wv, bv, th, out);
}